// Round 1
// baseline (171.093 us; speedup 1.0000x reference)
//
#include <hip/hip_runtime.h>
#include <math.h>

#define L_ 2048
#define NN 4096

// ws float offsets
#define OFF_Q   0u
#define OFF_K   1048576u
#define OFF_V   2097152u
#define OFF_QP  3145728u
#define OFF_KP  3342336u
#define OFF_VP  3538944u
#define OFF_RT  3932160u
#define OFF_S   3981312u

__device__ __forceinline__ float wsum64(float x) {
#pragma unroll
  for (int o = 32; o > 0; o >>= 1) x += __shfl_xor(x, o, 64);
  return x;
}

// ---------------- Kernel 1: q/k/v projections (32-node tiles, thread-owns-column)
__global__ __launch_bounds__(256) void k_proj_qkv(
    const float* __restrict__ hV,
    const float* __restrict__ Wq, const float* __restrict__ bq,
    const float* __restrict__ Wkv, const float* __restrict__ bkv,
    float* __restrict__ ws)
{
  __shared__ __align__(16) float hv[32][64];
  const int tid = threadIdx.x;
  const int node0 = blockIdx.x * 32;
  const int jc = blockIdx.y;
  for (int idx = tid; idx < 2048; idx += 256)
    hv[idx >> 6][idx & 63] = hV[(size_t)node0 * 64 + idx];
  __syncthreads();

  const int j = jc * 256 + tid;
  const float* Wcol; int stride; float bias;
  if (j < 256) { Wcol = Wq + j; stride = 256; bias = bq[j]; }
  else { const int jj = j - 256; Wcol = Wkv + jj; stride = 512; bias = bkv[jj]; }

  float acc[32];
#pragma unroll
  for (int n = 0; n < 32; ++n) acc[n] = 0.f;
  for (int i = 0; i < 64; i += 4) {
    const float w0 = Wcol[(i+0)*stride];
    const float w1 = Wcol[(i+1)*stride];
    const float w2 = Wcol[(i+2)*stride];
    const float w3 = Wcol[(i+3)*stride];
#pragma unroll
    for (int n = 0; n < 32; ++n) {
      const float4 h4 = *(const float4*)&hv[n][i];
      acc[n] = fmaf(h4.x, w0, fmaf(h4.y, w1, fmaf(h4.z, w2, fmaf(h4.w, w3, acc[n]))));
    }
  }
  float* qf = ws + OFF_Q;
  float* kf = ws + OFF_K;
  float* vf = ws + OFF_V;
  if (j < 256) {
#pragma unroll
    for (int n = 0; n < 32; ++n) qf[(size_t)(node0+n)*256 + j] = acc[n] + bias;
  } else {
    const int jj = j - 256; const int h = jj >> 7; const int r = jj & 127;
    float* dst = (r < 64) ? (kf + h*64 + r) : (vf + h*64 + (r - 64));
#pragma unroll
    for (int n = 0; n < 32; ++n) dst[(size_t)(node0+n)*256] = acc[n] + bias;
  }
}

// ---------------- Kernel 2: frames + point projections (global-frame k_pts/v_pts/q_pts)
__global__ __launch_bounds__(256) void k_proj_pts(
    const float* __restrict__ hV, const float* __restrict__ X,
    const float* __restrict__ Wqp, const float* __restrict__ bqp,
    const float* __restrict__ Wkvp, const float* __restrict__ bkvp,
    float* __restrict__ ws)
{
  __shared__ __align__(16) float hv[32][64];
  __shared__ float lin[32][192];
  __shared__ float rt[32][12];
  const int tid = threadIdx.x;
  const int node0 = blockIdx.x * 32;
  for (int idx = tid; idx < 2048; idx += 256)
    hv[idx >> 6][idx & 63] = hV[(size_t)node0 * 64 + idx];
  __syncthreads();

  if (tid < 192) {
    const float* Wcol; int stride; float bias;
    if (tid < 48) { Wcol = Wqp + tid; stride = 48; bias = bqp[tid]; }
    else { Wcol = Wkvp + (tid - 48); stride = 144; bias = bkvp[tid - 48]; }
    float acc[32];
#pragma unroll
    for (int n = 0; n < 32; ++n) acc[n] = 0.f;
    for (int i = 0; i < 64; i += 4) {
      const float w0 = Wcol[(i+0)*stride];
      const float w1 = Wcol[(i+1)*stride];
      const float w2 = Wcol[(i+2)*stride];
      const float w3 = Wcol[(i+3)*stride];
#pragma unroll
      for (int n = 0; n < 32; ++n) {
        const float4 h4 = *(const float4*)&hv[n][i];
        acc[n] = fmaf(h4.x, w0, fmaf(h4.y, w1, fmaf(h4.z, w2, fmaf(h4.w, w3, acc[n]))));
      }
    }
#pragma unroll
    for (int n = 0; n < 32; ++n) lin[n][tid] = acc[n] + bias;
  }
  float* rtw = ws + OFF_RT;
  if (tid < 32) {
    const float* x = X + (size_t)(node0 + tid) * 9;
    const float Nx=x[0]/10.f, Ny=x[1]/10.f, Nz=x[2]/10.f;
    const float Ax=x[3]/10.f, Ay=x[4]/10.f, Az=x[5]/10.f;
    const float Cx=x[6]/10.f, Cy=x[7]/10.f, Cz=x[8]/10.f;
    const float v1x=Cx-Ax, v1y=Cy-Ay, v1z=Cz-Az;
    const float v2x=Nx-Ax, v2y=Ny-Ay, v2z=Nz-Az;
    const float inv1 = 1.f/sqrtf(v1x*v1x+v1y*v1y+v1z*v1z);
    const float e1x=v1x*inv1, e1y=v1y*inv1, e1z=v1z*inv1;
    const float d12 = e1x*v2x+e1y*v2y+e1z*v2z;
    const float u2x=v2x-e1x*d12, u2y=v2y-e1y*d12, u2z=v2z-e1z*d12;
    const float inv2 = 1.f/sqrtf(u2x*u2x+u2y*u2y+u2z*u2z);
    const float e2x=u2x*inv2, e2y=u2y*inv2, e2z=u2z*inv2;
    const float e3x=e1y*e2z-e1z*e2y;
    const float e3y=e1z*e2x-e1x*e2z;
    const float e3z=e1x*e2y-e1y*e2x;
    const float r[12] = {e1x,e2x,e3x, e1y,e2y,e3y, e1z,e2z,e3z, Ax,Ay,Az};
#pragma unroll
    for (int q = 0; q < 12; ++q) { rt[tid][q] = r[q]; rtw[(size_t)(node0+tid)*12 + q] = r[q]; }
  }
  __syncthreads();
  float* qp = ws + OFF_QP;
  float* kp = ws + OFF_KP;
  float* vp = ws + OFF_VP;
  for (int item = tid; item < 2048; item += 256) {
    const int n = item >> 6, m = item & 63;
    const int node = node0 + n;
    float p0, p1, p2; float* dst;
    if (m < 16) {
      p0 = lin[n][m]; p1 = lin[n][16 + m]; p2 = lin[n][32 + m];
      dst = qp + (size_t)node*48 + m*3;
    } else {
      const int mm = m - 16;
      p0 = lin[n][48 + mm]; p1 = lin[n][96 + mm]; p2 = lin[n][144 + mm];
      const int h = mm / 12, pp = mm % 12;
      if (pp < 4) dst = kp + (size_t)node*48 + (h*4+pp)*3;
      else        dst = vp + (size_t)node*96 + (h*8+(pp-4))*3;
    }
    const float gx = rt[n][0]*p0 + rt[n][1]*p1 + rt[n][2]*p2 + rt[n][9];
    const float gy = rt[n][3]*p0 + rt[n][4]*p1 + rt[n][5]*p2 + rt[n][10];
    const float gz = rt[n][6]*p0 + rt[n][7]*p1 + rt[n][8]*p2 + rt[n][11];
    dst[0]=gx; dst[1]=gy; dst[2]=gz;
  }
}

// ---------------- Kernel 3: attention per node -> s(640)
__global__ __launch_bounds__(256) void k_attn(
    const float* __restrict__ hE, const int* __restrict__ Eidx,
    const float* __restrict__ maskAtt,
    const float* __restrict__ Wb, const float* __restrict__ bbv,
    const float* __restrict__ hwts,
    float* __restrict__ ws)
{
  __shared__ float sHE[32][65];   // padded: kills stride-64 bank conflict
  __shared__ __align__(16) float sQ[256];
  __shared__ __align__(16) float sQP[48];
  __shared__ float sRT[12];
  __shared__ int   sNbr[32];
  __shared__ float sLogit[32][4];
  __shared__ float sA[32][4];
  __shared__ float sS[640];
  const int tid = threadIdx.x;
  const int node = blockIdx.x;
  const int bat = node >> 11;           // node / L_
  const float* qf  = ws + OFF_Q;
  const float* kf  = ws + OFF_K;
  const float* vf  = ws + OFF_V;
  const float* qpw = ws + OFF_QP;
  const float* kpw = ws + OFF_KP;
  const float* vpw = ws + OFF_VP;
  const float* rtw = ws + OFF_RT;
  float* sw = ws + OFF_S;

  for (int idx = tid; idx < 2048; idx += 256)
    sHE[idx >> 6][idx & 63] = hE[(size_t)node*2048 + idx];
  sQ[tid] = qf[(size_t)node*256 + tid];
  if (tid < 48) sQP[tid] = qpw[(size_t)node*48 + tid];
  if (tid < 12) sRT[tid] = rtw[(size_t)node*12 + tid];
  if (tid < 32) sNbr[tid] = Eidx[(size_t)node*32 + tid];
  __syncthreads();

  if (tid < 128) {
    const int h = tid >> 5, kk = tid & 31;
    const int nb = bat * L_ + sNbr[kk];
    const float* krow = kf + (size_t)nb*256 + h*64;
    const float* qrow = &sQ[h*64];
    float dot = 0.f;
#pragma unroll
    for (int c = 0; c < 64; c += 4) {
      const float4 a4 = *(const float4*)&qrow[c];
      const float4 b4 = *(const float4*)&krow[c];
      dot = fmaf(a4.x,b4.x,fmaf(a4.y,b4.y,fmaf(a4.z,b4.z,fmaf(a4.w,b4.w,dot))));
    }
    float bt = 0.f;
#pragma unroll 8
    for (int i = 0; i < 64; ++i) bt = fmaf(sHE[kk][i], Wb[i*4 + h], bt);
    bt += bbv[h];
    const float* kprow = kpw + (size_t)nb*48 + h*12;
    const float* qprow = &sQP[h*12];
    float pt = 0.f;
#pragma unroll
    for (int u = 0; u < 12; ++u) { const float dd = qprow[u] - kprow[u]; pt = fmaf(dd, dd, pt); }
    const float hw = log1pf(expf(hwts[h]));
    const float lg = dot * 0.07216878364870322f          // 1/sqrt(3C)
                   + 0.5773502691896258f * bt             // sqrt(1/3)
                   - 0.5f * 0.1360827634879543f * hw * pt // sqrt(1/54)
                   + 100000.f * (maskAtt[(size_t)node*32 + kk] - 1.f);
    sLogit[kk][h] = lg;
  }
  __syncthreads();
  if (tid < 4) {
    const int h = tid;
    float m = -1e30f;
    for (int kk = 0; kk < 32; ++kk) m = fmaxf(m, sLogit[kk][h]);
    float ssum = 0.f;
    for (int kk = 0; kk < 32; ++kk) ssum += expf(sLogit[kk][h] - m);
    const float invs = 1.f / ssum;
    for (int kk = 0; kk < 32; ++kk) sA[kk][h] = expf(sLogit[kk][h] - m) * invs;
  }
  __syncthreads();
  {
    const int j = tid, h = tid >> 6, d = tid & 63;
    float o = 0.f, op = 0.f;
#pragma unroll 8
    for (int kk = 0; kk < 32; ++kk) {
      const float a = sA[kk][h];
      const int nb = bat * L_ + sNbr[kk];
      o  = fmaf(a, vf[(size_t)nb*256 + j], o);
      op = fmaf(a, sHE[kk][d], op);
    }
    sS[j] = o;
    sS[384 + j] = op;
  }
  if (tid < 32) {
    const int h = tid >> 3;
    float gx=0.f, gy=0.f, gz=0.f;
#pragma unroll 8
    for (int kk = 0; kk < 32; ++kk) {
      const float a = sA[kk][h];
      const int nb = bat * L_ + sNbr[kk];
      const float* vr = vpw + (size_t)nb*96 + tid*3;
      gx = fmaf(a, vr[0], gx);
      gy = fmaf(a, vr[1], gy);
      gz = fmaf(a, vr[2], gz);
    }
    const float dx = gx - sRT[9], dy = gy - sRT[10], dz = gz - sRT[11];
    const float l0 = sRT[0]*dx + sRT[3]*dy + sRT[6]*dz;   // R^T (g - t)
    const float l1 = sRT[1]*dx + sRT[4]*dy + sRT[7]*dz;
    const float l2 = sRT[2]*dx + sRT[5]*dy + sRT[8]*dz;
    sS[256 + tid] = l0;
    sS[288 + tid] = l1;
    sS[320 + tid] = l2;
    sS[352 + tid] = sqrtf(fmaf(l0,l0,fmaf(l1,l1,l2*l2)) + 1e-8f);
  }
  __syncthreads();
  for (int idx = tid; idx < 640; idx += 256)
    sw[(size_t)node*640 + idx] = sS[idx];
}

// ---------------- Kernel 4: s@Wout + LN0 + MLP + LN1 + mask (8-node tiles)
__global__ __launch_bounds__(256) void k_tail(
    const float* __restrict__ hV, const float* __restrict__ maskV,
    const float* __restrict__ Wout, const float* __restrict__ bout,
    const float* __restrict__ ln0g, const float* __restrict__ ln0b,
    const float* __restrict__ Wd1, const float* __restrict__ bd1,
    const float* __restrict__ Wd2, const float* __restrict__ bd2,
    const float* __restrict__ ln1g, const float* __restrict__ ln1b,
    const float* __restrict__ ws, float* __restrict__ out)
{
  __shared__ __align__(16) float sS[8][640];
  __shared__ float sPart[4][8][64];
  __shared__ float sH0[8][64];
  __shared__ float sHid[8][256];
  __shared__ float sY[8][64];
  const int tid = threadIdx.x;
  const int w = tid >> 6, lane = tid & 63;
  const int node0 = blockIdx.x * 8;
  const float* sw = ws + OFF_S;
  for (int idx = tid; idx < 5120; idx += 256)
    (&sS[0][0])[idx] = sw[(size_t)node0*640 + idx];
  __syncthreads();
  {
    float acc[8];
#pragma unroll
    for (int n = 0; n < 8; ++n) acc[n] = 0.f;
    for (int i = w*160; i < w*160+160; ++i) {
      const float wv = Wout[i*64 + lane];
#pragma unroll
      for (int n = 0; n < 8; ++n) acc[n] = fmaf(sS[n][i], wv, acc[n]);
    }
#pragma unroll
    for (int n = 0; n < 8; ++n) sPart[w][n][lane] = acc[n];
  }
  __syncthreads();
  for (int idx = tid; idx < 512; idx += 256) {
    const int n = idx >> 6, j = idx & 63;
    const float u = sPart[0][n][j] + sPart[1][n][j] + sPart[2][n][j] + sPart[3][n][j];
    sH0[n][j] = u + bout[j] + hV[(size_t)(node0+n)*64 + j];
  }
  __syncthreads();
#pragma unroll
  for (int rr = 0; rr < 2; ++rr) {
    const int n = w*2 + rr;
    const float x = sH0[n][lane];
    const float mu = wsum64(x) * 0.015625f;
    const float dv = x - mu;
    const float var = wsum64(dv*dv) * 0.015625f;
    sH0[n][lane] = dv * rsqrtf(var + 1e-5f) * ln0g[lane] + ln0b[lane];
  }
  __syncthreads();
  {
    float acc[8];
#pragma unroll
    for (int n = 0; n < 8; ++n) acc[n] = 0.f;
    for (int i = 0; i < 64; ++i) {
      const float wv = Wd1[i*256 + tid];
#pragma unroll
      for (int n = 0; n < 8; ++n) acc[n] = fmaf(sH0[n][i], wv, acc[n]);
    }
    const float b1 = bd1[tid];
#pragma unroll
    for (int n = 0; n < 8; ++n) sHid[n][tid] = fmaxf(acc[n] + b1, 0.f);
  }
  __syncthreads();
  {
    float acc[8];
#pragma unroll
    for (int n = 0; n < 8; ++n) acc[n] = 0.f;
    for (int i = w*64; i < w*64+64; ++i) {
      const float wv = Wd2[i*64 + lane];
#pragma unroll
      for (int n = 0; n < 8; ++n) acc[n] = fmaf(sHid[n][i], wv, acc[n]);
    }
#pragma unroll
    for (int n = 0; n < 8; ++n) sPart[w][n][lane] = acc[n];
  }
  __syncthreads();
  for (int idx = tid; idx < 512; idx += 256) {
    const int n = idx >> 6, j = idx & 63;
    const float u = sPart[0][n][j] + sPart[1][n][j] + sPart[2][n][j] + sPart[3][n][j];
    sY[n][j] = u + bd2[j] + sH0[n][j];
  }
  __syncthreads();
#pragma unroll
  for (int rr = 0; rr < 2; ++rr) {
    const int n = w*2 + rr;
    const float x = sY[n][lane];
    const float mu = wsum64(x) * 0.015625f;
    const float dv = x - mu;
    const float var = wsum64(dv*dv) * 0.015625f;
    const float hv1 = dv * rsqrtf(var + 1e-5f) * ln1g[lane] + ln1b[lane];
    out[(size_t)(node0+n)*64 + lane] = hv1 * maskV[node0 + n];
  }
}

extern "C" void kernel_launch(void* const* d_in, const int* in_sizes, int n_in,
                              void* d_out, int out_size, void* d_ws, size_t ws_size,
                              hipStream_t stream)
{
  const float* hV   = (const float*)d_in[0];
  const float* hE   = (const float*)d_in[1];
  const int*   Eidx = (const int*)  d_in[2];
  const float* X    = (const float*)d_in[3];
  const float* maskV= (const float*)d_in[4];
  const float* maskA= (const float*)d_in[5];
  const float* Wq   = (const float*)d_in[6];
  const float* bq   = (const float*)d_in[7];
  const float* Wkv  = (const float*)d_in[8];
  const float* bkv  = (const float*)d_in[9];
  const float* Wqp  = (const float*)d_in[10];
  const float* bqp  = (const float*)d_in[11];
  const float* Wkvp = (const float*)d_in[12];
  const float* bkvp = (const float*)d_in[13];
  const float* Wb   = (const float*)d_in[14];
  const float* bbv  = (const float*)d_in[15];
  const float* hwts = (const float*)d_in[16];
  const float* Wout = (const float*)d_in[17];
  const float* bout = (const float*)d_in[18];
  const float* ln0g = (const float*)d_in[19];
  const float* ln0b = (const float*)d_in[20];
  const float* ln1g = (const float*)d_in[21];
  const float* ln1b = (const float*)d_in[22];
  const float* Wd1  = (const float*)d_in[23];
  const float* bd1  = (const float*)d_in[24];
  const float* Wd2  = (const float*)d_in[25];
  const float* bd2  = (const float*)d_in[26];
  float* ws = (float*)d_ws;
  float* out = (float*)d_out;

  k_proj_qkv<<<dim3(128, 3), 256, 0, stream>>>(hV, Wq, bq, Wkv, bkv, ws);
  k_proj_pts<<<128, 256, 0, stream>>>(hV, X, Wqp, bqp, Wkvp, bkvp, ws);
  k_attn<<<4096, 256, 0, stream>>>(hE, Eidx, maskA, Wb, bbv, hwts, ws);
  k_tail<<<512, 256, 0, stream>>>(hV, maskV, Wout, bout, ln0g, ln0b,
                                  Wd1, bd1, Wd2, bd2, ln1g, ln1b, ws, out);
}

// Round 2
// 145.605 us; speedup vs baseline: 1.1750x; 1.1750x over previous
//
#include <hip/hip_runtime.h>
#include <math.h>

#define L_ 2048
#define NN 4096

// ws float offsets
#define OFF_Q   0u
#define OFF_K   1048576u
#define OFF_V   2097152u
#define OFF_QP  3145728u
#define OFF_KP  3342336u
#define OFF_VP  3538944u
#define OFF_RT  3932160u
#define OFF_S   3981312u

__device__ __forceinline__ float wsum64(float x) {
#pragma unroll
  for (int o = 32; o > 0; o >>= 1) x += __shfl_xor(x, o, 64);
  return x;
}

// ---------------- Kernel 1: merged projections
// blockIdx.y in [0,3): q/kv columns (32-node tiles, thread-owns-column)
// blockIdx.y == 3   : frames + point projections
__global__ __launch_bounds__(256) void k_proj(
    const float* __restrict__ hV, const float* __restrict__ X,
    const float* __restrict__ Wq, const float* __restrict__ bq,
    const float* __restrict__ Wkv, const float* __restrict__ bkv,
    const float* __restrict__ Wqp, const float* __restrict__ bqp,
    const float* __restrict__ Wkvp, const float* __restrict__ bkvp,
    float* __restrict__ ws)
{
  __shared__ __align__(16) float hv[32][64];
  __shared__ float lin[32][192];
  __shared__ float rt[32][12];
  const int tid = threadIdx.x;
  const int node0 = blockIdx.x * 32;
  for (int idx = tid; idx < 2048; idx += 256)
    hv[idx >> 6][idx & 63] = hV[(size_t)node0 * 64 + idx];
  __syncthreads();

  if (blockIdx.y < 3) {
    const int j = blockIdx.y * 256 + tid;
    const float* Wcol; int stride; float bias;
    if (j < 256) { Wcol = Wq + j; stride = 256; bias = bq[j]; }
    else { const int jj = j - 256; Wcol = Wkv + jj; stride = 512; bias = bkv[jj]; }

    float acc[32];
#pragma unroll
    for (int n = 0; n < 32; ++n) acc[n] = 0.f;
    for (int i = 0; i < 64; i += 4) {
      const float w0 = Wcol[(i+0)*stride];
      const float w1 = Wcol[(i+1)*stride];
      const float w2 = Wcol[(i+2)*stride];
      const float w3 = Wcol[(i+3)*stride];
#pragma unroll
      for (int n = 0; n < 32; ++n) {
        const float4 h4 = *(const float4*)&hv[n][i];
        acc[n] = fmaf(h4.x, w0, fmaf(h4.y, w1, fmaf(h4.z, w2, fmaf(h4.w, w3, acc[n]))));
      }
    }
    float* qf = ws + OFF_Q;
    float* kf = ws + OFF_K;
    float* vf = ws + OFF_V;
    if (j < 256) {
#pragma unroll
      for (int n = 0; n < 32; ++n) qf[(size_t)(node0+n)*256 + j] = acc[n] + bias;
    } else {
      const int jj = j - 256; const int h = jj >> 7; const int r = jj & 127;
      float* dst = (r < 64) ? (kf + h*64 + r) : (vf + h*64 + (r - 64));
#pragma unroll
      for (int n = 0; n < 32; ++n) dst[(size_t)(node0+n)*256] = acc[n] + bias;
    }
    return;
  }

  // ---- pts path
  if (tid < 192) {
    const float* Wcol; int stride; float bias;
    if (tid < 48) { Wcol = Wqp + tid; stride = 48; bias = bqp[tid]; }
    else { Wcol = Wkvp + (tid - 48); stride = 144; bias = bkvp[tid - 48]; }
    float acc[32];
#pragma unroll
    for (int n = 0; n < 32; ++n) acc[n] = 0.f;
    for (int i = 0; i < 64; i += 4) {
      const float w0 = Wcol[(i+0)*stride];
      const float w1 = Wcol[(i+1)*stride];
      const float w2 = Wcol[(i+2)*stride];
      const float w3 = Wcol[(i+3)*stride];
#pragma unroll
      for (int n = 0; n < 32; ++n) {
        const float4 h4 = *(const float4*)&hv[n][i];
        acc[n] = fmaf(h4.x, w0, fmaf(h4.y, w1, fmaf(h4.z, w2, fmaf(h4.w, w3, acc[n]))));
      }
    }
#pragma unroll
    for (int n = 0; n < 32; ++n) lin[n][tid] = acc[n] + bias;
  }
  float* rtw = ws + OFF_RT;
  if (tid < 32) {
    const float* x = X + (size_t)(node0 + tid) * 9;
    const float Nx=x[0]/10.f, Ny=x[1]/10.f, Nz=x[2]/10.f;
    const float Ax=x[3]/10.f, Ay=x[4]/10.f, Az=x[5]/10.f;
    const float Cx=x[6]/10.f, Cy=x[7]/10.f, Cz=x[8]/10.f;
    const float v1x=Cx-Ax, v1y=Cy-Ay, v1z=Cz-Az;
    const float v2x=Nx-Ax, v2y=Ny-Ay, v2z=Nz-Az;
    const float inv1 = 1.f/sqrtf(v1x*v1x+v1y*v1y+v1z*v1z);
    const float e1x=v1x*inv1, e1y=v1y*inv1, e1z=v1z*inv1;
    const float d12 = e1x*v2x+e1y*v2y+e1z*v2z;
    const float u2x=v2x-e1x*d12, u2y=v2y-e1y*d12, u2z=v2z-e1z*d12;
    const float inv2 = 1.f/sqrtf(u2x*u2x+u2y*u2y+u2z*u2z);
    const float e2x=u2x*inv2, e2y=u2y*inv2, e2z=u2z*inv2;
    const float e3x=e1y*e2z-e1z*e2y;
    const float e3y=e1z*e2x-e1x*e2z;
    const float e3z=e1x*e2y-e1y*e2x;
    const float r[12] = {e1x,e2x,e3x, e1y,e2y,e3y, e1z,e2z,e3z, Ax,Ay,Az};
#pragma unroll
    for (int q = 0; q < 12; ++q) { rt[tid][q] = r[q]; rtw[(size_t)(node0+tid)*12 + q] = r[q]; }
  }
  __syncthreads();
  float* qp = ws + OFF_QP;
  float* kp = ws + OFF_KP;
  float* vp = ws + OFF_VP;
  for (int item = tid; item < 2048; item += 256) {
    const int n = item >> 6, m = item & 63;
    const int node = node0 + n;
    float p0, p1, p2; float* dst;
    if (m < 16) {
      p0 = lin[n][m]; p1 = lin[n][16 + m]; p2 = lin[n][32 + m];
      dst = qp + (size_t)node*48 + m*3;
    } else {
      const int mm = m - 16;
      p0 = lin[n][48 + mm]; p1 = lin[n][96 + mm]; p2 = lin[n][144 + mm];
      const int h = mm / 12, pp = mm % 12;
      if (pp < 4) dst = kp + (size_t)node*48 + (h*4+pp)*3;
      else        dst = vp + (size_t)node*96 + (h*8+(pp-4))*3;
    }
    const float gx = rt[n][0]*p0 + rt[n][1]*p1 + rt[n][2]*p2 + rt[n][9];
    const float gy = rt[n][3]*p0 + rt[n][4]*p1 + rt[n][5]*p2 + rt[n][10];
    const float gz = rt[n][6]*p0 + rt[n][7]*p1 + rt[n][8]*p2 + rt[n][11];
    dst[0]=gx; dst[1]=gy; dst[2]=gz;
  }
}

// ---------------- Kernel 2: attention per node -> s(640), wave-synchronous
__global__ __launch_bounds__(256) void k_attn(
    const float* __restrict__ hE, const int* __restrict__ Eidx,
    const float* __restrict__ maskAtt,
    const float* __restrict__ Wb, const float* __restrict__ bbv,
    const float* __restrict__ hwts,
    float* __restrict__ ws)
{
  __shared__ float sA[32][4];
  __shared__ float sG[96];
  const int tid = threadIdx.x;
  const int node = blockIdx.x;
  const int bat = node >> 11;
  const float* qf  = ws + OFF_Q;
  const float* kf  = ws + OFF_K;
  const float* vf  = ws + OFF_V;
  const float* qpw = ws + OFF_QP;
  const float* kpw = ws + OFF_KP;
  const float* vpw = ws + OFF_VP;
  const float* rtw = ws + OFF_RT;
  float* sw = ws + OFF_S;

  // ---- phase 1: logits + softmax, one wave per head, no barrier needed
  {
    const int h = tid >> 6, lane = tid & 63, kk = lane >> 1, c2 = lane & 1;
    const int nb = bat*L_ + Eidx[(size_t)node*32 + kk];
    const float* krow = kf + (size_t)nb*256 + h*64 + c2*32;
    const float* qrow = qf + (size_t)node*256 + h*64 + c2*32;
    float dot = 0.f;
#pragma unroll
    for (int c = 0; c < 32; c += 4) {
      const float4 k4 = *(const float4*)&krow[c];
      const float4 q4 = *(const float4*)&qrow[c];
      dot = fmaf(q4.x,k4.x,fmaf(q4.y,k4.y,fmaf(q4.z,k4.z,fmaf(q4.w,k4.w,dot))));
    }
    const float* he  = hE + (size_t)node*2048 + kk*64 + c2*32;
    const float* wbp = Wb + c2*128 + h;        // (c2*32+i)*4 + h
    float bt = 0.f;
#pragma unroll
    for (int i = 0; i < 32; i += 4) {
      const float4 he4 = *(const float4*)&he[i];
      bt = fmaf(he4.x, wbp[(i+0)*4],
           fmaf(he4.y, wbp[(i+1)*4],
           fmaf(he4.z, wbp[(i+2)*4],
           fmaf(he4.w, wbp[(i+3)*4], bt))));
    }
    const float* qpr = qpw + (size_t)node*48 + h*12 + c2*6;
    const float* kpr = kpw + (size_t)nb*48 + h*12 + c2*6;
    float pt = 0.f;
#pragma unroll
    for (int u = 0; u < 6; ++u) { const float dd = qpr[u]-kpr[u]; pt = fmaf(dd,dd,pt); }
    dot += __shfl_xor(dot, 1, 64);
    bt  += __shfl_xor(bt, 1, 64);
    pt  += __shfl_xor(pt, 1, 64);
    const float hw = log1pf(expf(hwts[h]));
    const float lg = 0.07216878364870322f*dot                 // 1/sqrt(3C)
                   + 0.5773502691896258f*(bt + bbv[h])        // sqrt(1/3)
                   - 0.06804138174397717f*hw*pt               // 0.5*sqrt(1/54)
                   + 100000.f*(maskAtt[(size_t)node*32 + kk] - 1.f);
    float m = lg;
#pragma unroll
    for (int o = 2; o <= 32; o <<= 1) m = fmaxf(m, __shfl_xor(m, o, 64));
    const float e = expf(lg - m);
    float ssum = e;
#pragma unroll
    for (int o = 2; o <= 32; o <<= 1) ssum += __shfl_xor(ssum, o, 64);
    if (c2 == 0) sA[kk][h] = e / ssum;
  }
  __syncthreads();

  // ---- phase 2: aggregation (o, o_pair all threads; o_pt components on tid<96)
  const int h2 = tid >> 6, d = tid & 63;
  float o = 0.f, op = 0.f;
#pragma unroll
  for (int kk = 0; kk < 32; ++kk) {
    const float a = sA[kk][h2];
    const int nb = bat*L_ + Eidx[(size_t)node*32 + kk];   // uniform -> s_load
    o  = fmaf(a, vf[(size_t)nb*256 + tid], o);
    op = fmaf(a, hE[(size_t)node*2048 + kk*64 + d], op);
  }
  float* srow = sw + (size_t)node*640;
  srow[tid] = o;
  srow[384 + tid] = op;
  if (tid < 96) {
    const int h3 = tid / 24;      // t = (h*8+p)*3 + x
    float g = 0.f;
#pragma unroll
    for (int kk = 0; kk < 32; ++kk) {
      const int nb = bat*L_ + Eidx[(size_t)node*32 + kk];
      g = fmaf(sA[kk][h3], vpw[(size_t)nb*96 + tid], g);
    }
    sG[tid] = g;
  }
  __syncthreads();
  if (tid < 32) {
    const float* rt = rtw + (size_t)node*12;
    const float gx = sG[tid*3], gy = sG[tid*3+1], gz = sG[tid*3+2];
    const float dx = gx - rt[9], dy = gy - rt[10], dz = gz - rt[11];
    const float l0 = rt[0]*dx + rt[3]*dy + rt[6]*dz;   // R^T (g - t)
    const float l1 = rt[1]*dx + rt[4]*dy + rt[7]*dz;
    const float l2 = rt[2]*dx + rt[5]*dy + rt[8]*dz;
    srow[256 + tid] = l0;
    srow[288 + tid] = l1;
    srow[320 + tid] = l2;
    srow[352 + tid] = sqrtf(fmaf(l0,l0,fmaf(l1,l1,l2*l2)) + 1e-8f);
  }
}

// ---------------- Kernel 3: s@Wout + LN0 + MLP + LN1 + mask (8-node tiles)
__global__ __launch_bounds__(256) void k_tail(
    const float* __restrict__ hV, const float* __restrict__ maskV,
    const float* __restrict__ Wout, const float* __restrict__ bout,
    const float* __restrict__ ln0g, const float* __restrict__ ln0b,
    const float* __restrict__ Wd1, const float* __restrict__ bd1,
    const float* __restrict__ Wd2, const float* __restrict__ bd2,
    const float* __restrict__ ln1g, const float* __restrict__ ln1b,
    const float* __restrict__ ws, float* __restrict__ out)
{
  __shared__ __align__(16) float sS[8][640];
  __shared__ float sPart[4][8][64];
  __shared__ float sH0[8][64];
  __shared__ float sHid[8][256];
  __shared__ float sY[8][64];
  const int tid = threadIdx.x;
  const int w = tid >> 6, lane = tid & 63;
  const int node0 = blockIdx.x * 8;
  const float* sw = ws + OFF_S;
  for (int idx = tid; idx < 5120; idx += 256)
    (&sS[0][0])[idx] = sw[(size_t)node0*640 + idx];
  __syncthreads();
  {
    float acc[8];
#pragma unroll
    for (int n = 0; n < 8; ++n) acc[n] = 0.f;
    for (int i = w*160; i < w*160+160; ++i) {
      const float wv = Wout[i*64 + lane];
#pragma unroll
      for (int n = 0; n < 8; ++n) acc[n] = fmaf(sS[n][i], wv, acc[n]);
    }
#pragma unroll
    for (int n = 0; n < 8; ++n) sPart[w][n][lane] = acc[n];
  }
  __syncthreads();
  for (int idx = tid; idx < 512; idx += 256) {
    const int n = idx >> 6, j = idx & 63;
    const float u = sPart[0][n][j] + sPart[1][n][j] + sPart[2][n][j] + sPart[3][n][j];
    sH0[n][j] = u + bout[j] + hV[(size_t)(node0+n)*64 + j];
  }
  __syncthreads();
#pragma unroll
  for (int rr = 0; rr < 2; ++rr) {
    const int n = w*2 + rr;
    const float x = sH0[n][lane];
    const float mu = wsum64(x) * 0.015625f;
    const float dv = x - mu;
    const float var = wsum64(dv*dv) * 0.015625f;
    sH0[n][lane] = dv * rsqrtf(var + 1e-5f) * ln0g[lane] + ln0b[lane];
  }
  __syncthreads();
  {
    float acc[8];
#pragma unroll
    for (int n = 0; n < 8; ++n) acc[n] = 0.f;
    for (int i = 0; i < 64; ++i) {
      const float wv = Wd1[i*256 + tid];
#pragma unroll
      for (int n = 0; n < 8; ++n) acc[n] = fmaf(sH0[n][i], wv, acc[n]);
    }
    const float b1 = bd1[tid];
#pragma unroll
    for (int n = 0; n < 8; ++n) sHid[n][tid] = fmaxf(acc[n] + b1, 0.f);
  }
  __syncthreads();
  {
    float acc[8];
#pragma unroll
    for (int n = 0; n < 8; ++n) acc[n] = 0.f;
    for (int i = w*64; i < w*64+64; ++i) {
      const float wv = Wd2[i*64 + lane];
#pragma unroll
      for (int n = 0; n < 8; ++n) acc[n] = fmaf(sHid[n][i], wv, acc[n]);
    }
#pragma unroll
    for (int n = 0; n < 8; ++n) sPart[w][n][lane] = acc[n];
  }
  __syncthreads();
  for (int idx = tid; idx < 512; idx += 256) {
    const int n = idx >> 6, j = idx & 63;
    const float u = sPart[0][n][j] + sPart[1][n][j] + sPart[2][n][j] + sPart[3][n][j];
    sY[n][j] = u + bd2[j] + sH0[n][j];
  }
  __syncthreads();
#pragma unroll
  for (int rr = 0; rr < 2; ++rr) {
    const int n = w*2 + rr;
    const float x = sY[n][lane];
    const float mu = wsum64(x) * 0.015625f;
    const float dv = x - mu;
    const float var = wsum64(dv*dv) * 0.015625f;
    const float hv1 = dv * rsqrtf(var + 1e-5f) * ln1g[lane] + ln1b[lane];
    out[(size_t)(node0+n)*64 + lane] = hv1 * maskV[node0 + n];
  }
}

extern "C" void kernel_launch(void* const* d_in, const int* in_sizes, int n_in,
                              void* d_out, int out_size, void* d_ws, size_t ws_size,
                              hipStream_t stream)
{
  const float* hV   = (const float*)d_in[0];
  const float* hE   = (const float*)d_in[1];
  const int*   Eidx = (const int*)  d_in[2];
  const float* X    = (const float*)d_in[3];
  const float* maskV= (const float*)d_in[4];
  const float* maskA= (const float*)d_in[5];
  const float* Wq   = (const float*)d_in[6];
  const float* bq   = (const float*)d_in[7];
  const float* Wkv  = (const float*)d_in[8];
  const float* bkv  = (const float*)d_in[9];
  const float* Wqp  = (const float*)d_in[10];
  const float* bqp  = (const float*)d_in[11];
  const float* Wkvp = (const float*)d_in[12];
  const float* bkvp = (const float*)d_in[13];
  const float* Wb   = (const float*)d_in[14];
  const float* bbv  = (const float*)d_in[15];
  const float* hwts = (const float*)d_in[16];
  const float* Wout = (const float*)d_in[17];
  const float* bout = (const float*)d_in[18];
  const float* ln0g = (const float*)d_in[19];
  const float* ln0b = (const float*)d_in[20];
  const float* ln1g = (const float*)d_in[21];
  const float* ln1b = (const float*)d_in[22];
  const float* Wd1  = (const float*)d_in[23];
  const float* bd1  = (const float*)d_in[24];
  const float* Wd2  = (const float*)d_in[25];
  const float* bd2  = (const float*)d_in[26];
  float* ws = (float*)d_ws;
  float* out = (float*)d_out;

  k_proj<<<dim3(128, 4), 256, 0, stream>>>(hV, X, Wq, bq, Wkv, bkv,
                                           Wqp, bqp, Wkvp, bkvp, ws);
  k_attn<<<4096, 256, 0, stream>>>(hE, Eidx, maskA, Wb, bbv, hwts, ws);
  k_tail<<<512, 256, 0, stream>>>(hV, maskV, Wout, bout, ln0g, ln0b,
                                  Wd1, bd1, Wd2, bd2, ln1g, ln1b, ws, out);
}

// Round 4
// 126.931 us; speedup vs baseline: 1.3479x; 1.1471x over previous
//
#include <hip/hip_runtime.h>
#include <math.h>

#define L_ 2048
#define NN 4096

// ws float offsets
#define OFF_Q   0u
#define OFF_K   1048576u
#define OFF_V   2097152u
#define OFF_QP  3145728u
#define OFF_KP  3342336u
#define OFF_VP  3538944u
#define OFF_RT  3932160u
#define OFF_S   3981312u

__device__ __forceinline__ float wsum64(float x) {
#pragma unroll
  for (int o = 32; o > 0; o >>= 1) x += __shfl_xor(x, o, 64);
  return x;
}

// ---------------- Kernel 1: merged projections
__global__ __launch_bounds__(256) void k_proj(
    const float* __restrict__ hV, const float* __restrict__ X,
    const float* __restrict__ Wq, const float* __restrict__ bq,
    const float* __restrict__ Wkv, const float* __restrict__ bkv,
    const float* __restrict__ Wqp, const float* __restrict__ bqp,
    const float* __restrict__ Wkvp, const float* __restrict__ bkvp,
    float* __restrict__ ws)
{
  __shared__ __align__(16) float hv[32][64];
  __shared__ float lin[32][192];
  __shared__ float rt[32][12];
  const int tid = threadIdx.x;
  const int node0 = blockIdx.x * 32;
  for (int idx = tid; idx < 512; idx += 256)
    *(float4*)&hv[idx >> 4][(idx & 15) * 4] = *(const float4*)&hV[(size_t)node0*64 + idx*4];
  __syncthreads();

  if (blockIdx.y < 3) {
    const int j = blockIdx.y * 256 + tid;
    const float* Wcol; int stride; float bias;
    if (j < 256) { Wcol = Wq + j; stride = 256; bias = bq[j]; }
    else { const int jj = j - 256; Wcol = Wkv + jj; stride = 512; bias = bkv[jj]; }

    float acc[32];
#pragma unroll
    for (int n = 0; n < 32; ++n) acc[n] = 0.f;
    for (int i = 0; i < 64; i += 4) {
      const float w0 = Wcol[(i+0)*stride];
      const float w1 = Wcol[(i+1)*stride];
      const float w2 = Wcol[(i+2)*stride];
      const float w3 = Wcol[(i+3)*stride];
#pragma unroll
      for (int n = 0; n < 32; ++n) {
        const float4 h4 = *(const float4*)&hv[n][i];
        acc[n] = fmaf(h4.x, w0, fmaf(h4.y, w1, fmaf(h4.z, w2, fmaf(h4.w, w3, acc[n]))));
      }
    }
    float* qf = ws + OFF_Q;
    float* kf = ws + OFF_K;
    float* vf = ws + OFF_V;
    if (j < 256) {
#pragma unroll
      for (int n = 0; n < 32; ++n) qf[(size_t)(node0+n)*256 + j] = acc[n] + bias;
    } else {
      const int jj = j - 256; const int h = jj >> 7; const int r = jj & 127;
      float* dst = (r < 64) ? (kf + h*64 + r) : (vf + h*64 + (r - 64));
#pragma unroll
      for (int n = 0; n < 32; ++n) dst[(size_t)(node0+n)*256] = acc[n] + bias;
    }
    return;
  }

  // ---- pts path
  if (tid < 192) {
    const float* Wcol; int stride; float bias;
    if (tid < 48) { Wcol = Wqp + tid; stride = 48; bias = bqp[tid]; }
    else { Wcol = Wkvp + (tid - 48); stride = 144; bias = bkvp[tid - 48]; }
    float acc[32];
#pragma unroll
    for (int n = 0; n < 32; ++n) acc[n] = 0.f;
    for (int i = 0; i < 64; i += 4) {
      const float w0 = Wcol[(i+0)*stride];
      const float w1 = Wcol[(i+1)*stride];
      const float w2 = Wcol[(i+2)*stride];
      const float w3 = Wcol[(i+3)*stride];
#pragma unroll
      for (int n = 0; n < 32; ++n) {
        const float4 h4 = *(const float4*)&hv[n][i];
        acc[n] = fmaf(h4.x, w0, fmaf(h4.y, w1, fmaf(h4.z, w2, fmaf(h4.w, w3, acc[n]))));
      }
    }
#pragma unroll
    for (int n = 0; n < 32; ++n) lin[n][tid] = acc[n] + bias;
  }
  float* rtw = ws + OFF_RT;
  if (tid < 32) {
    const float* x = X + (size_t)(node0 + tid) * 9;
    const float Nx=x[0]/10.f, Ny=x[1]/10.f, Nz=x[2]/10.f;
    const float Ax=x[3]/10.f, Ay=x[4]/10.f, Az=x[5]/10.f;
    const float Cx=x[6]/10.f, Cy=x[7]/10.f, Cz=x[8]/10.f;
    const float v1x=Cx-Ax, v1y=Cy-Ay, v1z=Cz-Az;
    const float v2x=Nx-Ax, v2y=Ny-Ay, v2z=Nz-Az;
    const float inv1 = 1.f/sqrtf(v1x*v1x+v1y*v1y+v1z*v1z);
    const float e1x=v1x*inv1, e1y=v1y*inv1, e1z=v1z*inv1;
    const float d12 = e1x*v2x+e1y*v2y+e1z*v2z;
    const float u2x=v2x-e1x*d12, u2y=v2y-e1y*d12, u2z=v2z-e1z*d12;
    const float inv2 = 1.f/sqrtf(u2x*u2x+u2y*u2y+u2z*u2z);
    const float e2x=u2x*inv2, e2y=u2y*inv2, e2z=u2z*inv2;
    const float e3x=e1y*e2z-e1z*e2y;
    const float e3y=e1z*e2x-e1x*e2z;
    const float e3z=e1x*e2y-e1y*e2x;
    const float r[12] = {e1x,e2x,e3x, e1y,e2y,e3y, e1z,e2z,e3z, Ax,Ay,Az};
#pragma unroll
    for (int q = 0; q < 12; ++q) { rt[tid][q] = r[q]; rtw[(size_t)(node0+tid)*12 + q] = r[q]; }
  }
  __syncthreads();
  float* qp = ws + OFF_QP;
  float* kp = ws + OFF_KP;
  float* vp = ws + OFF_VP;
  for (int item = tid; item < 2048; item += 256) {
    const int n = item >> 6, m = item & 63;
    const int node = node0 + n;
    float p0, p1, p2; float* dst;
    if (m < 16) {
      p0 = lin[n][m]; p1 = lin[n][16 + m]; p2 = lin[n][32 + m];
      dst = qp + (size_t)node*48 + m*3;
    } else {
      const int mm = m - 16;
      p0 = lin[n][48 + mm]; p1 = lin[n][96 + mm]; p2 = lin[n][144 + mm];
      const int h = mm / 12, pp = mm % 12;
      if (pp < 4) dst = kp + (size_t)node*48 + (h*4+pp)*3;
      else        dst = vp + (size_t)node*96 + (h*8+(pp-4))*3;
    }
    const float gx = rt[n][0]*p0 + rt[n][1]*p1 + rt[n][2]*p2 + rt[n][9];
    const float gy = rt[n][3]*p0 + rt[n][4]*p1 + rt[n][5]*p2 + rt[n][10];
    const float gz = rt[n][6]*p0 + rt[n][7]*p1 + rt[n][8]*p2 + rt[n][11];
    dst[0]=gx; dst[1]=gy; dst[2]=gz;
  }
}

// ---------------- Kernel 2: attention per node -> s(640)
// hE staged once in padded LDS; 16-deep MLP on gathers; batch-aware XCD swizzle.
__global__ __launch_bounds__(256) void k_attn(
    const float* __restrict__ hE, const int* __restrict__ Eidx,
    const float* __restrict__ maskAtt,
    const float* __restrict__ Wb, const float* __restrict__ bbv,
    const float* __restrict__ hwts,
    float* __restrict__ ws)
{
  __shared__ float sHE[32][65];
  __shared__ float sAh[4][32];
  __shared__ float sG[96];
  const int tid = threadIdx.x;
  // batch-aware XCD swizzle: XCDs 0-3 get batch 0, XCDs 4-7 batch 1
  const int rb = blockIdx.x & 7, qb = blockIdx.x >> 3;
  const int bat = rb >> 2;
  const int node = bat * L_ + (rb & 3) * 512 + qb;
  const float* qf  = ws + OFF_Q;
  const float* kf  = ws + OFF_K;
  const float* vf  = ws + OFF_V;
  const float* qpw = ws + OFF_QP;
  const float* kpw = ws + OFF_KP;
  const float* vpw = ws + OFF_VP;
  const float* rtw = ws + OFF_RT;
  float* sw = ws + OFF_S;

  // stage hE row (8KB) once
  for (int idx = tid; idx < 512; idx += 256) {
    const float4 v4 = *(const float4*)&hE[(size_t)node*2048 + idx*4];
    const int kk = idx >> 4, c = (idx & 15) * 4;
    sHE[kk][c] = v4.x; sHE[kk][c+1] = v4.y; sHE[kk][c+2] = v4.z; sHE[kk][c+3] = v4.w;
  }
  __syncthreads();

  // ---- phase 1: logits + softmax, one wave per head
  {
    const int h = tid >> 6, lane = tid & 63, kk = lane >> 1, c2 = lane & 1;
    const int nb = bat*L_ + Eidx[(size_t)node*32 + kk];
    const float* krow = kf + (size_t)nb*256 + h*64 + c2*32;
    const float* qrow = qf + (size_t)node*256 + h*64 + c2*32;
    float dot = 0.f;
#pragma unroll
    for (int c = 0; c < 32; c += 4) {
      const float4 k4 = *(const float4*)&krow[c];
      const float4 q4 = *(const float4*)&qrow[c];
      dot = fmaf(q4.x,k4.x,fmaf(q4.y,k4.y,fmaf(q4.z,k4.z,fmaf(q4.w,k4.w,dot))));
    }
    const float* wbp = Wb + c2*128 + h;        // (c2*32+i)*4 + h
    float bt = 0.f;
#pragma unroll
    for (int i = 0; i < 32; ++i)
      bt = fmaf(sHE[kk][c2*32 + i], wbp[i*4], bt);
    const float* qpr = qpw + (size_t)node*48 + h*12 + c2*6;
    const float* kpr = kpw + (size_t)nb*48 + h*12 + c2*6;
    float pt = 0.f;
#pragma unroll
    for (int u = 0; u < 6; u += 2) {
      const float2 qp2 = *(const float2*)&qpr[u];
      const float2 kp2 = *(const float2*)&kpr[u];
      const float d0 = qp2.x - kp2.x, d1 = qp2.y - kp2.y;
      pt = fmaf(d0, d0, fmaf(d1, d1, pt));
    }
    dot += __shfl_xor(dot, 1, 64);
    bt  += __shfl_xor(bt, 1, 64);
    pt  += __shfl_xor(pt, 1, 64);
    const float hw = log1pf(expf(hwts[h]));
    const float lg = 0.07216878364870322f*dot
                   + 0.5773502691896258f*(bt + bbv[h])
                   - 0.06804138174397717f*hw*pt
                   + 100000.f*(maskAtt[(size_t)node*32 + kk] - 1.f);
    float m = lg;
#pragma unroll
    for (int o = 2; o <= 32; o <<= 1) m = fmaxf(m, __shfl_xor(m, o, 64));
    const float e = expf(lg - m);
    float ssum = e;
#pragma unroll
    for (int o = 2; o <= 32; o <<= 1) ssum += __shfl_xor(ssum, o, 64);
    if (c2 == 0) sAh[h][kk] = e / ssum;
  }
  __syncthreads();

  // ---- phase 2: aggregation with deep MLP
  const int h2 = tid >> 6, d = tid & 63;
  float a[32];
#pragma unroll
  for (int kk4 = 0; kk4 < 32; kk4 += 4) {
    const float4 t = *(const float4*)&sAh[h2][kk4];
    a[kk4] = t.x; a[kk4+1] = t.y; a[kk4+2] = t.z; a[kk4+3] = t.w;
  }
  float* srow = sw + (size_t)node*640;
  float o = 0.f, op = 0.f;
#pragma unroll
  for (int c0 = 0; c0 < 32; c0 += 16) {
    float vv[16];
#pragma unroll
    for (int u = 0; u < 16; ++u) {
      const int nb = bat*L_ + Eidx[(size_t)node*32 + c0 + u];  // uniform -> s_load
      vv[u] = vf[(size_t)nb*256 + tid];
    }
#pragma unroll
    for (int u = 0; u < 16; ++u) {
      o  = fmaf(a[c0+u], vv[u], o);
      op = fmaf(a[c0+u], sHE[c0+u][d], op);
    }
  }
  srow[tid] = o;
  srow[384 + tid] = op;

  if (tid < 96) {
    const int h3 = tid / 24;
    float g = 0.f;
#pragma unroll
    for (int c0 = 0; c0 < 32; c0 += 16) {
      float pv[16];
#pragma unroll
      for (int u = 0; u < 16; ++u) {
        const int nb = bat*L_ + Eidx[(size_t)node*32 + c0 + u];
        pv[u] = vpw[(size_t)nb*96 + tid];
      }
#pragma unroll
      for (int u = 0; u < 16; ++u) g = fmaf(sAh[h3][c0+u], pv[u], g);
    }
    sG[tid] = g;
  }
  __syncthreads();
  if (tid < 32) {
    const float* rt = rtw + (size_t)node*12;
    const float gx = sG[tid*3], gy = sG[tid*3+1], gz = sG[tid*3+2];
    const float dx = gx - rt[9], dy = gy - rt[10], dz = gz - rt[11];
    const float l0 = rt[0]*dx + rt[3]*dy + rt[6]*dz;
    const float l1 = rt[1]*dx + rt[4]*dy + rt[7]*dz;
    const float l2 = rt[2]*dx + rt[5]*dy + rt[8]*dz;
    srow[256 + tid] = l0;
    srow[288 + tid] = l1;
    srow[320 + tid] = l2;
    srow[352 + tid] = sqrtf(fmaf(l0,l0,fmaf(l1,l1,l2*l2)) + 1e-8f);
  }
}

// ---------------- Kernel 3: s@Wout + LN0 + MLP + LN1 + mask (8-node tiles)
__global__ __launch_bounds__(256) void k_tail(
    const float* __restrict__ hV, const float* __restrict__ maskV,
    const float* __restrict__ Wout, const float* __restrict__ bout,
    const float* __restrict__ ln0g, const float* __restrict__ ln0b,
    const float* __restrict__ Wd1, const float* __restrict__ bd1,
    const float* __restrict__ Wd2, const float* __restrict__ bd2,
    const float* __restrict__ ln1g, const float* __restrict__ ln1b,
    const float* __restrict__ ws, float* __restrict__ out)
{
  __shared__ __align__(16) float sS[8][640];
  __shared__ float sPart[4][8][64];
  __shared__ float sH0[8][64];
  __shared__ float sHid[8][256];
  __shared__ float sY[8][64];
  const int tid = threadIdx.x;
  const int w = tid >> 6, lane = tid & 63;
  const int node0 = blockIdx.x * 8;
  const float* sw = ws + OFF_S;
  for (int idx = tid; idx < 1280; idx += 256)
    *(float4*)&(&sS[0][0])[idx*4] = *(const float4*)&sw[(size_t)node0*640 + idx*4];
  __syncthreads();
  {
    float acc[8];
#pragma unroll
    for (int n = 0; n < 8; ++n) acc[n] = 0.f;
    for (int i = w*160; i < w*160+160; ++i) {
      const float wv = Wout[i*64 + lane];
#pragma unroll
      for (int n = 0; n < 8; ++n) acc[n] = fmaf(sS[n][i], wv, acc[n]);
    }
#pragma unroll
    for (int n = 0; n < 8; ++n) sPart[w][n][lane] = acc[n];
  }
  __syncthreads();
  for (int idx = tid; idx < 512; idx += 256) {
    const int n = idx >> 6, j = idx & 63;
    const float u = sPart[0][n][j] + sPart[1][n][j] + sPart[2][n][j] + sPart[3][n][j];
    sH0[n][j] = u + bout[j] + hV[(size_t)(node0+n)*64 + j];
  }
  __syncthreads();
#pragma unroll
  for (int rr = 0; rr < 2; ++rr) {
    const int n = w*2 + rr;
    const float x = sH0[n][lane];
    const float mu = wsum64(x) * 0.015625f;
    const float dv = x - mu;
    const float var = wsum64(dv*dv) * 0.015625f;
    sH0[n][lane] = dv * rsqrtf(var + 1e-5f) * ln0g[lane] + ln0b[lane];
  }
  __syncthreads();
  {
    float acc[8];
#pragma unroll
    for (int n = 0; n < 8; ++n) acc[n] = 0.f;
    for (int i = 0; i < 64; ++i) {
      const float wv = Wd1[i*256 + tid];
#pragma unroll
      for (int n = 0; n < 8; ++n) acc[n] = fmaf(sH0[n][i], wv, acc[n]);
    }
    const float b1 = bd1[tid];
#pragma unroll
    for (int n = 0; n < 8; ++n) sHid[n][tid] = fmaxf(acc[n] + b1, 0.f);
  }
  __syncthreads();
  {
    float acc[8];
#pragma unroll
    for (int n = 0; n < 8; ++n) acc[n] = 0.f;
    for (int i = w*64; i < w*64+64; ++i) {
      const float wv = Wd2[i*64 + lane];
#pragma unroll
      for (int n = 0; n < 8; ++n) acc[n] = fmaf(sHid[n][i], wv, acc[n]);
    }
#pragma unroll
    for (int n = 0; n < 8; ++n) sPart[w][n][lane] = acc[n];
  }
  __syncthreads();
  for (int idx = tid; idx < 512; idx += 256) {
    const int n = idx >> 6, j = idx & 63;
    const float u = sPart[0][n][j] + sPart[1][n][j] + sPart[2][n][j] + sPart[3][n][j];
    sY[n][j] = u + bd2[j] + sH0[n][j];
  }
  __syncthreads();
#pragma unroll
  for (int rr = 0; rr < 2; ++rr) {
    const int n = w*2 + rr;
    const float x = sY[n][lane];
    const float mu = wsum64(x) * 0.015625f;
    const float dv = x - mu;
    const float var = wsum64(dv*dv) * 0.015625f;
    const float hv1 = dv * rsqrtf(var + 1e-5f) * ln1g[lane] + ln1b[lane];
    out[(size_t)(node0+n)*64 + lane] = hv1 * maskV[node0 + n];
  }
}

extern "C" void kernel_launch(void* const* d_in, const int* in_sizes, int n_in,
                              void* d_out, int out_size, void* d_ws, size_t ws_size,
                              hipStream_t stream)
{
  const float* hV   = (const float*)d_in[0];
  const float* hE   = (const float*)d_in[1];
  const int*   Eidx = (const int*)  d_in[2];
  const float* X    = (const float*)d_in[3];
  const float* maskV= (const float*)d_in[4];
  const float* maskA= (const float*)d_in[5];
  const float* Wq   = (const float*)d_in[6];
  const float* bq   = (const float*)d_in[7];
  const float* Wkv  = (const float*)d_in[8];
  const float* bkv  = (const float*)d_in[9];
  const float* Wqp  = (const float*)d_in[10];
  const float* bqp  = (const float*)d_in[11];
  const float* Wkvp = (const float*)d_in[12];
  const float* bkvp = (const float*)d_in[13];
  const float* Wb   = (const float*)d_in[14];
  const float* bbv  = (const float*)d_in[15];
  const float* hwts = (const float*)d_in[16];
  const float* Wout = (const float*)d_in[17];
  const float* bout = (const float*)d_in[18];
  const float* ln0g = (const float*)d_in[19];
  const float* ln0b = (const float*)d_in[20];
  const float* ln1g = (const float*)d_in[21];
  const float* ln1b = (const float*)d_in[22];
  const float* Wd1  = (const float*)d_in[23];
  const float* bd1  = (const float*)d_in[24];
  const float* Wd2  = (const float*)d_in[25];
  const float* bd2  = (const float*)d_in[26];
  float* ws = (float*)d_ws;
  float* out = (float*)d_out;

  k_proj<<<dim3(128, 4), 256, 0, stream>>>(hV, X, Wq, bq, Wkv, bkv,
                                           Wqp, bqp, Wkvp, bkvp, ws);
  k_attn<<<4096, 256, 0, stream>>>(hE, Eidx, maskA, Wb, bbv, hwts, ws);
  k_tail<<<512, 256, 0, stream>>>(hV, maskV, Wout, bout, ln0g, ln0b,
                                  Wd1, bd1, Wd2, bd2, ln1g, ln1b, ws, out);
}

// Round 5
// 91.093 us; speedup vs baseline: 1.8782x; 1.3934x over previous
//
#include <hip/hip_runtime.h>
#include <hip/hip_bf16.h>
#include <math.h>

#define L_ 2048
#define NN 4096

// ws float offsets (kf/vf regions reinterpreted as bf16; sizes shrink, offsets kept)
#define OFF_Q   0u
#define OFF_K   1048576u
#define OFF_V   2097152u
#define OFF_QP  3145728u
#define OFF_KP  3342336u
#define OFF_VP  3538944u
#define OFF_RT  3932160u
#define OFF_S   3981312u

__device__ __forceinline__ float wsum64(float x) {
#pragma unroll
  for (int o = 32; o > 0; o >>= 1) x += __shfl_xor(x, o, 64);
  return x;
}

__device__ __forceinline__ float bf_lo(unsigned u) { return __uint_as_float(u << 16); }
__device__ __forceinline__ float bf_hi(unsigned u) { return __uint_as_float(u & 0xffff0000u); }

// ---------------- Kernel 1: merged projections
__global__ __launch_bounds__(256) void k_proj(
    const float* __restrict__ hV, const float* __restrict__ X,
    const float* __restrict__ Wq, const float* __restrict__ bq,
    const float* __restrict__ Wkv, const float* __restrict__ bkv,
    const float* __restrict__ Wqp, const float* __restrict__ bqp,
    const float* __restrict__ Wkvp, const float* __restrict__ bkvp,
    float* __restrict__ ws)
{
  __shared__ __align__(16) float hv[32][64];
  __shared__ float lin[32][192];
  __shared__ float rt[32][12];
  const int tid = threadIdx.x;
  const int node0 = blockIdx.x * 32;
  for (int idx = tid; idx < 512; idx += 256)
    *(float4*)&hv[idx >> 4][(idx & 15) * 4] = *(const float4*)&hV[(size_t)node0*64 + idx*4];
  __syncthreads();

  if (blockIdx.y < 3) {
    const int j = blockIdx.y * 256 + tid;
    const float* Wcol; int stride; float bias;
    if (j < 256) { Wcol = Wq + j; stride = 256; bias = bq[j]; }
    else { const int jj = j - 256; Wcol = Wkv + jj; stride = 512; bias = bkv[jj]; }

    float acc[32];
#pragma unroll
    for (int n = 0; n < 32; ++n) acc[n] = 0.f;
    for (int i = 0; i < 64; i += 4) {
      const float w0 = Wcol[(i+0)*stride];
      const float w1 = Wcol[(i+1)*stride];
      const float w2 = Wcol[(i+2)*stride];
      const float w3 = Wcol[(i+3)*stride];
#pragma unroll
      for (int n = 0; n < 32; ++n) {
        const float4 h4 = *(const float4*)&hv[n][i];
        acc[n] = fmaf(h4.x, w0, fmaf(h4.y, w1, fmaf(h4.z, w2, fmaf(h4.w, w3, acc[n]))));
      }
    }
    float* qf = ws + OFF_Q;
    __hip_bfloat16* kfb = (__hip_bfloat16*)(ws + OFF_K);
    __hip_bfloat16* vfb = (__hip_bfloat16*)(ws + OFF_V);
    if (j < 256) {
#pragma unroll
      for (int n = 0; n < 32; ++n) qf[(size_t)(node0+n)*256 + j] = acc[n] + bias;
    } else {
      const int jj = j - 256; const int h = jj >> 7; const int r = jj & 127;
      __hip_bfloat16* dst = (r < 64) ? (kfb + h*64 + r) : (vfb + h*64 + (r - 64));
#pragma unroll
      for (int n = 0; n < 32; ++n) dst[(size_t)(node0+n)*256] = __float2bfloat16(acc[n] + bias);
    }
    return;
  }

  // ---- pts path
  if (tid < 192) {
    const float* Wcol; int stride; float bias;
    if (tid < 48) { Wcol = Wqp + tid; stride = 48; bias = bqp[tid]; }
    else { Wcol = Wkvp + (tid - 48); stride = 144; bias = bkvp[tid - 48]; }
    float acc[32];
#pragma unroll
    for (int n = 0; n < 32; ++n) acc[n] = 0.f;
    for (int i = 0; i < 64; i += 4) {
      const float w0 = Wcol[(i+0)*stride];
      const float w1 = Wcol[(i+1)*stride];
      const float w2 = Wcol[(i+2)*stride];
      const float w3 = Wcol[(i+3)*stride];
#pragma unroll
      for (int n = 0; n < 32; ++n) {
        const float4 h4 = *(const float4*)&hv[n][i];
        acc[n] = fmaf(h4.x, w0, fmaf(h4.y, w1, fmaf(h4.z, w2, fmaf(h4.w, w3, acc[n]))));
      }
    }
#pragma unroll
    for (int n = 0; n < 32; ++n) lin[n][tid] = acc[n] + bias;
  }
  float* rtw = ws + OFF_RT;
  if (tid < 32) {
    const float* x = X + (size_t)(node0 + tid) * 9;
    const float Nx=x[0]/10.f, Ny=x[1]/10.f, Nz=x[2]/10.f;
    const float Ax=x[3]/10.f, Ay=x[4]/10.f, Az=x[5]/10.f;
    const float Cx=x[6]/10.f, Cy=x[7]/10.f, Cz=x[8]/10.f;
    const float v1x=Cx-Ax, v1y=Cy-Ay, v1z=Cz-Az;
    const float v2x=Nx-Ax, v2y=Ny-Ay, v2z=Nz-Az;
    const float inv1 = 1.f/sqrtf(v1x*v1x+v1y*v1y+v1z*v1z);
    const float e1x=v1x*inv1, e1y=v1y*inv1, e1z=v1z*inv1;
    const float d12 = e1x*v2x+e1y*v2y+e1z*v2z;
    const float u2x=v2x-e1x*d12, u2y=v2y-e1y*d12, u2z=v2z-e1z*d12;
    const float inv2 = 1.f/sqrtf(u2x*u2x+u2y*u2y+u2z*u2z);
    const float e2x=u2x*inv2, e2y=u2y*inv2, e2z=u2z*inv2;
    const float e3x=e1y*e2z-e1z*e2y;
    const float e3y=e1z*e2x-e1x*e2z;
    const float e3z=e1x*e2y-e1y*e2x;
    const float r[12] = {e1x,e2x,e3x, e1y,e2y,e3y, e1z,e2z,e3z, Ax,Ay,Az};
#pragma unroll
    for (int q = 0; q < 12; ++q) { rt[tid][q] = r[q]; rtw[(size_t)(node0+tid)*12 + q] = r[q]; }
  }
  __syncthreads();
  float* qp = ws + OFF_QP;
  float* kp = ws + OFF_KP;
  float* vp = ws + OFF_VP;
  for (int item = tid; item < 2048; item += 256) {
    const int n = item >> 6, m = item & 63;
    const int node = node0 + n;
    float p0, p1, p2; float* dst;
    if (m < 16) {
      p0 = lin[n][m]; p1 = lin[n][16 + m]; p2 = lin[n][32 + m];
      dst = qp + (size_t)node*48 + m*3;
    } else {
      const int mm = m - 16;
      p0 = lin[n][48 + mm]; p1 = lin[n][96 + mm]; p2 = lin[n][144 + mm];
      const int h = mm / 12, pp = mm % 12;
      if (pp < 4) dst = kp + (size_t)node*48 + (h*4+pp)*3;
      else        dst = vp + (size_t)node*96 + (h*8+(pp-4))*3;
    }
    const float gx = rt[n][0]*p0 + rt[n][1]*p1 + rt[n][2]*p2 + rt[n][9];
    const float gy = rt[n][3]*p0 + rt[n][4]*p1 + rt[n][5]*p2 + rt[n][10];
    const float gz = rt[n][6]*p0 + rt[n][7]*p1 + rt[n][8]*p2 + rt[n][11];
    dst[0]=gx; dst[1]=gy; dst[2]=gz;
  }
}

// ---------------- Kernel 2: attention per node -> s(640)
// bf16 k/v gathers (L2-resident); hE staged once in padded LDS; 16-deep MLP.
__global__ __launch_bounds__(256) void k_attn(
    const float* __restrict__ hE, const int* __restrict__ Eidx,
    const float* __restrict__ maskAtt,
    const float* __restrict__ Wb, const float* __restrict__ bbv,
    const float* __restrict__ hwts,
    float* __restrict__ ws)
{
  __shared__ float sHE[32][65];
  __shared__ float sAh[4][32];
  __shared__ float sG[96];
  const int tid = threadIdx.x;
  // batch-aware XCD swizzle: XCDs 0-3 get batch 0, XCDs 4-7 batch 1
  const int rb = blockIdx.x & 7, qb = blockIdx.x >> 3;
  const int bat = rb >> 2;
  const int node = bat * L_ + (rb & 3) * 512 + qb;
  const float* qf  = ws + OFF_Q;
  const __hip_bfloat16* kfb = (const __hip_bfloat16*)(ws + OFF_K);
  const __hip_bfloat16* vfb = (const __hip_bfloat16*)(ws + OFF_V);
  const float* qpw = ws + OFF_QP;
  const float* kpw = ws + OFF_KP;
  const float* vpw = ws + OFF_VP;
  const float* rtw = ws + OFF_RT;
  float* sw = ws + OFF_S;

  // issue per-lane gather metadata loads early (ILP with hE staging)
  const int h = tid >> 6, lane = tid & 63, kk = lane >> 1, c2 = lane & 1;
  const int nbr  = Eidx[(size_t)node*32 + kk];
  const float mval = maskAtt[(size_t)node*32 + kk];

  // stage hE row (8KB) once
  for (int idx = tid; idx < 512; idx += 256) {
    const float4 v4 = *(const float4*)&hE[(size_t)node*2048 + idx*4];
    const int r = idx >> 4, c = (idx & 15) * 4;
    sHE[r][c] = v4.x; sHE[r][c+1] = v4.y; sHE[r][c+2] = v4.z; sHE[r][c+3] = v4.w;
  }
  __syncthreads();

  // ---- phase 1: logits + softmax, one wave per head
  {
    const int nb = bat*L_ + nbr;
    const uint4* krow4 = (const uint4*)(kfb + (size_t)nb*256 + h*64 + c2*32);
    const float4* qrow4 = (const float4*)(qf + (size_t)node*256 + h*64 + c2*32);
    float dot = 0.f;
#pragma unroll
    for (int c = 0; c < 4; ++c) {
      const uint4 kb = krow4[c];            // 8 bf16
      const float4 qa = qrow4[2*c], qb2 = qrow4[2*c+1];
      dot = fmaf(qa.x, bf_lo(kb.x), dot);
      dot = fmaf(qa.y, bf_hi(kb.x), dot);
      dot = fmaf(qa.z, bf_lo(kb.y), dot);
      dot = fmaf(qa.w, bf_hi(kb.y), dot);
      dot = fmaf(qb2.x, bf_lo(kb.z), dot);
      dot = fmaf(qb2.y, bf_hi(kb.z), dot);
      dot = fmaf(qb2.z, bf_lo(kb.w), dot);
      dot = fmaf(qb2.w, bf_hi(kb.w), dot);
    }
    const float* wbp = Wb + c2*128 + h;        // (c2*32+i)*4 + h
    float bt = 0.f;
#pragma unroll
    for (int i = 0; i < 32; ++i)
      bt = fmaf(sHE[kk][c2*32 + i], wbp[i*4], bt);
    const float* qpr = qpw + (size_t)node*48 + h*12 + c2*6;
    const float* kpr = kpw + (size_t)nb*48 + h*12 + c2*6;
    float pt = 0.f;
#pragma unroll
    for (int u = 0; u < 6; u += 2) {
      const float2 qp2 = *(const float2*)&qpr[u];
      const float2 kp2 = *(const float2*)&kpr[u];
      const float d0 = qp2.x - kp2.x, d1 = qp2.y - kp2.y;
      pt = fmaf(d0, d0, fmaf(d1, d1, pt));
    }
    dot += __shfl_xor(dot, 1, 64);
    bt  += __shfl_xor(bt, 1, 64);
    pt  += __shfl_xor(pt, 1, 64);
    const float hw = log1pf(expf(hwts[h]));
    const float lg = 0.07216878364870322f*dot
                   + 0.5773502691896258f*(bt + bbv[h])
                   - 0.06804138174397717f*hw*pt
                   + 100000.f*(mval - 1.f);
    float m = lg;
#pragma unroll
    for (int o = 2; o <= 32; o <<= 1) m = fmaxf(m, __shfl_xor(m, o, 64));
    const float e = __expf(lg - m);
    float ssum = e;
#pragma unroll
    for (int o = 2; o <= 32; o <<= 1) ssum += __shfl_xor(ssum, o, 64);
    if (c2 == 0) sAh[h][kk] = e / ssum;
  }
  __syncthreads();

  // ---- phase 2: aggregation with deep MLP on gathers
  const int h2 = tid >> 6, d = tid & 63;
  float a[32];
#pragma unroll
  for (int kk4 = 0; kk4 < 32; kk4 += 4) {
    const float4 t = *(const float4*)&sAh[h2][kk4];
    a[kk4] = t.x; a[kk4+1] = t.y; a[kk4+2] = t.z; a[kk4+3] = t.w;
  }
  float* srow = sw + (size_t)node*640;
  float o = 0.f, op = 0.f;
#pragma unroll
  for (int c0 = 0; c0 < 32; c0 += 16) {
    float vv[16];
#pragma unroll
    for (int u = 0; u < 16; ++u) {
      const int nb = bat*L_ + Eidx[(size_t)node*32 + c0 + u];  // uniform -> s_load
      vv[u] = __bfloat162float(vfb[(size_t)nb*256 + tid]);
    }
#pragma unroll
    for (int u = 0; u < 16; ++u) {
      o  = fmaf(a[c0+u], vv[u], o);
      op = fmaf(a[c0+u], sHE[c0+u][d], op);
    }
  }
  srow[tid] = o;
  srow[384 + tid] = op;

  if (tid < 96) {
    const int h3 = tid / 24;
    float g = 0.f;
#pragma unroll
    for (int c0 = 0; c0 < 32; c0 += 16) {
      float pv[16];
#pragma unroll
      for (int u = 0; u < 16; ++u) {
        const int nb = bat*L_ + Eidx[(size_t)node*32 + c0 + u];
        pv[u] = vpw[(size_t)nb*96 + tid];
      }
#pragma unroll
      for (int u = 0; u < 16; ++u) g = fmaf(sAh[h3][c0+u], pv[u], g);
    }
    sG[tid] = g;
  }
  __syncthreads();
  if (tid < 32) {
    const float* rt = rtw + (size_t)node*12;
    const float gx = sG[tid*3], gy = sG[tid*3+1], gz = sG[tid*3+2];
    const float dx = gx - rt[9], dy = gy - rt[10], dz = gz - rt[11];
    const float l0 = rt[0]*dx + rt[3]*dy + rt[6]*dz;
    const float l1 = rt[1]*dx + rt[4]*dy + rt[7]*dz;
    const float l2 = rt[2]*dx + rt[5]*dy + rt[8]*dz;
    srow[256 + tid] = l0;
    srow[288 + tid] = l1;
    srow[320 + tid] = l2;
    srow[352 + tid] = sqrtf(fmaf(l0,l0,fmaf(l1,l1,l2*l2)) + 1e-8f);
  }
}

// ---------------- Kernel 3: s@Wout + LN0 + MLP + LN1 + mask (4-node tiles, 1024 blocks)
__global__ __launch_bounds__(256) void k_tail(
    const float* __restrict__ hV, const float* __restrict__ maskV,
    const float* __restrict__ Wout, const float* __restrict__ bout,
    const float* __restrict__ ln0g, const float* __restrict__ ln0b,
    const float* __restrict__ Wd1, const float* __restrict__ bd1,
    const float* __restrict__ Wd2, const float* __restrict__ bd2,
    const float* __restrict__ ln1g, const float* __restrict__ ln1b,
    const float* __restrict__ ws, float* __restrict__ out)
{
  __shared__ __align__(16) float sS[4][640];
  __shared__ float sPart[4][4][64];
  __shared__ float sH0[4][64];
  __shared__ float sHid[4][256];
  __shared__ float sY[4][64];
  const int tid = threadIdx.x;
  const int w = tid >> 6, lane = tid & 63;
  const int node0 = blockIdx.x * 4;
  const float* sw = ws + OFF_S;
  for (int idx = tid; idx < 640; idx += 256)
    *(float4*)&(&sS[0][0])[idx*4] = *(const float4*)&sw[(size_t)node0*640 + idx*4];
  __syncthreads();
  {
    float acc[4];
#pragma unroll
    for (int n = 0; n < 4; ++n) acc[n] = 0.f;
    for (int i = w*160; i < w*160+160; ++i) {
      const float wv = Wout[i*64 + lane];
#pragma unroll
      for (int n = 0; n < 4; ++n) acc[n] = fmaf(sS[n][i], wv, acc[n]);
    }
#pragma unroll
    for (int n = 0; n < 4; ++n) sPart[w][n][lane] = acc[n];
  }
  __syncthreads();
  {
    const int n = tid >> 6, j = tid & 63;
    const float u = sPart[0][n][j] + sPart[1][n][j] + sPart[2][n][j] + sPart[3][n][j];
    sH0[n][j] = u + bout[j] + hV[(size_t)(node0+n)*64 + j];
  }
  __syncthreads();
  {
    const int n = w;
    const float x = sH0[n][lane];
    const float mu = wsum64(x) * 0.015625f;
    const float dv = x - mu;
    const float var = wsum64(dv*dv) * 0.015625f;
    sH0[n][lane] = dv * rsqrtf(var + 1e-5f) * ln0g[lane] + ln0b[lane];
  }
  __syncthreads();
  {
    float acc[4];
#pragma unroll
    for (int n = 0; n < 4; ++n) acc[n] = 0.f;
    for (int i = 0; i < 64; ++i) {
      const float wv = Wd1[i*256 + tid];
#pragma unroll
      for (int n = 0; n < 4; ++n) acc[n] = fmaf(sH0[n][i], wv, acc[n]);
    }
    const float b1 = bd1[tid];
#pragma unroll
    for (int n = 0; n < 4; ++n) sHid[n][tid] = fmaxf(acc[n] + b1, 0.f);
  }
  __syncthreads();
  {
    float acc[4];
#pragma unroll
    for (int n = 0; n < 4; ++n) acc[n] = 0.f;
    for (int i = w*64; i < w*64+64; ++i) {
      const float wv = Wd2[i*64 + lane];
#pragma unroll
      for (int n = 0; n < 4; ++n) acc[n] = fmaf(sHid[n][i], wv, acc[n]);
    }
#pragma unroll
    for (int n = 0; n < 4; ++n) sPart[w][n][lane] = acc[n];
  }
  __syncthreads();
  {
    const int n = tid >> 6, j = tid & 63;
    const float u = sPart[0][n][j] + sPart[1][n][j] + sPart[2][n][j] + sPart[3][n][j];
    sY[n][j] = u + bd2[j] + sH0[n][j];
  }
  __syncthreads();
  {
    const int n = w;
    const float x = sY[n][lane];
    const float mu = wsum64(x) * 0.015625f;
    const float dv = x - mu;
    const float var = wsum64(dv*dv) * 0.015625f;
    const float hv1 = dv * rsqrtf(var + 1e-5f) * ln1g[lane] + ln1b[lane];
    out[(size_t)(node0+n)*64 + lane] = hv1 * maskV[node0 + n];
  }
}

extern "C" void kernel_launch(void* const* d_in, const int* in_sizes, int n_in,
                              void* d_out, int out_size, void* d_ws, size_t ws_size,
                              hipStream_t stream)
{
  const float* hV   = (const float*)d_in[0];
  const float* hE   = (const float*)d_in[1];
  const int*   Eidx = (const int*)  d_in[2];
  const float* X    = (const float*)d_in[3];
  const float* maskV= (const float*)d_in[4];
  const float* maskA= (const float*)d_in[5];
  const float* Wq   = (const float*)d_in[6];
  const float* bq   = (const float*)d_in[7];
  const float* Wkv  = (const float*)d_in[8];
  const float* bkv  = (const float*)d_in[9];
  const float* Wqp  = (const float*)d_in[10];
  const float* bqp  = (const float*)d_in[11];
  const float* Wkvp = (const float*)d_in[12];
  const float* bkvp = (const float*)d_in[13];
  const float* Wb   = (const float*)d_in[14];
  const float* bbv  = (const float*)d_in[15];
  const float* hwts = (const float*)d_in[16];
  const float* Wout = (const float*)d_in[17];
  const float* bout = (const float*)d_in[18];
  const float* ln0g = (const float*)d_in[19];
  const float* ln0b = (const float*)d_in[20];
  const float* ln1g = (const float*)d_in[21];
  const float* ln1b = (const float*)d_in[22];
  const float* Wd1  = (const float*)d_in[23];
  const float* bd1  = (const float*)d_in[24];
  const float* Wd2  = (const float*)d_in[25];
  const float* bd2  = (const float*)d_in[26];
  float* ws = (float*)d_ws;
  float* out = (float*)d_out;

  k_proj<<<dim3(128, 4), 256, 0, stream>>>(hV, X, Wq, bq, Wkv, bkv,
                                           Wqp, bqp, Wkvp, bkvp, ws);
  k_attn<<<4096, 256, 0, stream>>>(hE, Eidx, maskA, Wb, bbv, hwts, ws);
  k_tail<<<1024, 256, 0, stream>>>(hV, maskV, Wout, bout, ln0g, ln0b,
                                   Wd1, bd1, Wd2, bd2, ln1g, ln1b, ws, out);
}